// Round 9
// baseline (5254.617 us; speedup 1.0000x reference)
//
#include <hip/hip_runtime.h>
#include <hip/hip_fp16.h>
#include <cstdint>

typedef _Float16 half8 __attribute__((ext_vector_type(8)));
typedef _Float16 half4 __attribute__((ext_vector_type(4)));
typedef float f32x4 __attribute__((ext_vector_type(4)));

#define MFMA_F16 __builtin_amdgcn_mfma_f32_16x16x32_f16
#define PIN(x)   asm volatile("" : "+v"(x))
#define LD_RLX(p)   __hip_atomic_load((p),  __ATOMIC_RELAXED, __HIP_MEMORY_SCOPE_AGENT)
#define LD_ACQ(p)   __hip_atomic_load((p),  __ATOMIC_ACQUIRE, __HIP_MEMORY_SCOPE_AGENT)
#define ST_REL(p,v) __hip_atomic_store((p),(v), __ATOMIC_RELEASE, __HIP_MEMORY_SCOPE_AGENT)

__device__ __forceinline__ float fast_rcp(float x){
#if __has_builtin(__builtin_amdgcn_rcpf)
  return __builtin_amdgcn_rcpf(x);
#else
  return 1.0f/x;
#endif
}
__device__ __forceinline__ float fast_exp2(float x){
#if __has_builtin(__builtin_amdgcn_exp2f)
  return __builtin_amdgcn_exp2f(x);
#else
  return exp2f(x);
#endif
}
__device__ __forceinline__ float sigm_f(float x){
  return fast_rcp(1.0f + fast_exp2(-1.44269504f*x));
}
__device__ __forceinline__ float tanh_fast(float x){
  float e = fast_exp2(-2.88539008f*x);            // e^(-2x)
  return fmaf(2.0f, fast_rcp(1.0f + e), -1.0f);   // 2/(1+e) - 1
}

// Weak barrier: LDS visibility only. Strong barrier: full vmcnt drain,
// used only at 16-step flag boundaries (release/acquire protocol).
__device__ __forceinline__ void bar_weak(){
  asm volatile("s_waitcnt lgkmcnt(0)" ::: "memory");
  __builtin_amdgcn_s_barrier();
  asm volatile("" ::: "memory");
}
__device__ __forceinline__ void bar_strong(){
  asm volatile("s_waitcnt vmcnt(0) lgkmcnt(0)" ::: "memory");
  __builtin_amdgcn_s_barrier();
  asm volatile("" ::: "memory");
}

// Self-quantizing fragment load (bit-identical to reference fake-quant).
__device__ __forceinline__ half8 qfrag(const float* __restrict__ W, int tile,
                                       int kb, int l, float scale){
  int row = tile*16 + (l & 15);
  int k0  = kb*32 + (l >> 4)*8;
  const float4* p = (const float4*)&W[row*256 + k0];
  float4 a = p[0], b = p[1];
  half8 h;
  h[0] = (_Float16)(rintf(a.x/scale)*scale);
  h[1] = (_Float16)(rintf(a.y/scale)*scale);
  h[2] = (_Float16)(rintf(a.z/scale)*scale);
  h[3] = (_Float16)(rintf(a.w/scale)*scale);
  h[4] = (_Float16)(rintf(b.x/scale)*scale);
  h[5] = (_Float16)(rintf(b.y/scale)*scale);
  h[6] = (_Float16)(rintf(b.z/scale)*scale);
  h[7] = (_Float16)(rintf(b.w/scale)*scale);
  return h;
}

// ---------------------------------------------------------------------------
// Phase A1: per-matrix max|w|
// ---------------------------------------------------------------------------
__global__ __launch_bounds__(256) void k_maxabs(
    const float* __restrict__ w0, const float* __restrict__ w1,
    const float* __restrict__ w2, const float* __restrict__ w3,
    int n, int* __restrict__ slots)
{
  const float* srcs[4] = {w0, w1, w2, w3};
  int m    = blockIdx.x >> 5;
  int part = blockIdx.x & 31;
  const float* w = srcs[m];
  float loc = 0.0f;
  for (int i = part*256 + threadIdx.x; i < n; i += 32*256)
    loc = fmaxf(loc, fabsf(w[i]));
  for (int off = 32; off; off >>= 1)
    loc = fmaxf(loc, __shfl_down(loc, off, 64));
  __shared__ float red[4];
  int wv = threadIdx.x >> 6;
  if ((threadIdx.x & 63) == 0) red[wv] = loc;
  __syncthreads();
  if (threadIdx.x == 0) {
    float mx = fmaxf(fmaxf(red[0], red[1]), fmaxf(red[2], red[3]));
    atomicMax(&slots[m], __float_as_int(mx));
  }
}

// ---------------------------------------------------------------------------
// Phase A2: x f32 -> fp16 in A-fragment layout.
// ---------------------------------------------------------------------------
__global__ __launch_bounds__(256) void k_xcast(
    const float* __restrict__ x, _Float16* __restrict__ xh)
{
  int n = blockIdx.x*256 + threadIdx.x;           // 4,194,304 total
  int t   = n >> 13;
  int rem = n & 8191;
  int bg  = rem >> 5;
  int k8  = rem & 31;
  const float4* src = (const float4*)&x[((size_t)t*256 + bg)*256 + k8*8];
  float4 v0 = src[0], v1 = src[1];
  half8 hv;
  hv[0] = (_Float16)v0.x; hv[1] = (_Float16)v0.y;
  hv[2] = (_Float16)v0.z; hv[3] = (_Float16)v0.w;
  hv[4] = (_Float16)v1.x; hv[5] = (_Float16)v1.y;
  hv[6] = (_Float16)v1.z; hv[7] = (_Float16)v1.w;
  int bb = bg >> 4, b = bg & 15, kb = k8 >> 2, lane = (k8 & 3)*16 + b;
  *(half8*)&xh[(size_t)t*65536 + (size_t)bb*4096 + kb*512 + lane*8] = hv;
}

// ---------------------------------------------------------------------------
// Fused pipeline: 80 blocks x 512 thr.
//   role 0..7   : layer-1 GRU, TWO bb per block (2r, 2r+1), phase-skewed.
//   role 8..15  : layer-2 GRU, same.
//   role 16..47 : gemm2 producers (h1seq @ W_ih2^T -> gi2 ring).
//   role 48..79 : gemm1 producers (xh @ W_ih1^T -> gi1 ring).
// GRU segments: segA = GATE(bb0,t) || MFMA(bb1,t); segB = MFMA(bb0,t+1) ||
// GATE(bb1,t). Each barrier-to-barrier window mixes MFMA-pipe and VALU/trans
// work from independent streams -> pipes overlap instead of convoy.
// ---------------------------------------------------------------------------
__global__ __launch_bounds__(512, 2) void k_pipe(
    const _Float16* __restrict__ xh,
    const float* __restrict__ wih1, const float* __restrict__ bih1,
    _Float16* __restrict__ gi1, const float* __restrict__ whh1,
    const float* __restrict__ bhh1, float* __restrict__ hc1,
    _Float16* __restrict__ h1seq,
    const float* __restrict__ wih2, const float* __restrict__ bih2,
    const float* __restrict__ bhh2, const float* __restrict__ whh2,
    float* __restrict__ hc2, _Float16* __restrict__ gi2,
    const int* __restrict__ slots,
    int* __restrict__ flag0, int* __restrict__ flag1,
    int* __restrict__ flag2, int* __restrict__ flag3)
{
  __shared__ __align__(16) _Float16 hl[8192];     // 16 KB: hl0 | hl1
  const int role = blockIdx.x;
  const int tid  = threadIdx.x;
  const int w = tid >> 6, l = tid & 63, q = l >> 4, c16 = l & 15;

  if (role >= 16) {
    // ------------- gemm producers (gemm1: 48..79, gemm2: 16..47) -----------
    const bool G1 = (role >= 48);
    const int id = G1 ? role - 48 : role - 16;
    const int bb = id >> 1, par = id & 1;
    const float*    Wsrc = G1 ? wih1  : wih2;
    const float*    bihp = G1 ? bih1  : bih2;
    const float*    bhhp = G1 ? bhh1  : bhh2;
    const _Float16* Asrc = G1 ? xh    : h1seq;
    _Float16*       gout = G1 ? gi1   : gi2;
    const float sc = __int_as_float(slots[G1 ? 0 : 2]) * (1.0f/127.0f);

    float bR[2], bZ[2], bN[2];
    half8 wr[2][8], wz[2][8], wn[2][8];
    #pragma unroll
    for (int nt = 0; nt < 2; nt++) {
      const int j = w*32 + nt*16 + c16;
      bR[nt] = bihp[j]       + bhhp[j];
      bZ[nt] = bihp[256 + j] + bhhp[256 + j];
      bN[nt] = bihp[512 + j];
      #pragma unroll
      for (int kb = 0; kb < 8; kb++) {
        wr[nt][kb] = qfrag(Wsrc,      2*w + nt, kb, l, sc);  PIN(wr[nt][kb]);
        wz[nt][kb] = qfrag(Wsrc, 16 + 2*w + nt, kb, l, sc);  PIN(wz[nt][kb]);
        wn[nt][kb] = qfrag(Wsrc, 32 + 2*w + nt, kb, l, sc);  PIN(wn[nt][kb]);
      }
    }

    for (int g = par; g < 32; g += 2) {
      const int t0 = g*16;
      if (tid == 0) {
        if (!G1) {
          while (LD_RLX(&flag1[bb]) < t0 + 16) __builtin_amdgcn_s_sleep(10);
          if (g >= 4)
            while (LD_RLX(&flag3[bb]) < (g - 3)*16) __builtin_amdgcn_s_sleep(10);
          (void)LD_ACQ(&flag1[bb]);
        } else if (g >= 4) {
          while (LD_RLX(&flag1[bb]) < (g - 3)*16) __builtin_amdgcn_s_sleep(10);
          (void)LD_ACQ(&flag1[bb]);
        }
      }
      __syncthreads();
      for (int t = t0; t < t0 + 16; t++) {
        const _Float16* ap = Asrc + (size_t)t*65536 + (size_t)bb*4096 + l*8;
        f32x4 aR[2], aZ[2], aN[2];
        #pragma unroll
        for (int nt = 0; nt < 2; nt++) {
          aR[nt] = (f32x4){0.f,0.f,0.f,0.f};
          aZ[nt] = (f32x4){0.f,0.f,0.f,0.f};
          aN[nt] = (f32x4){0.f,0.f,0.f,0.f};
        }
        #pragma unroll
        for (int kb = 0; kb < 8; kb++) {
          half8 a = *(const half8*)&ap[kb*512];
          #pragma unroll
          for (int nt = 0; nt < 2; nt++) {
            aR[nt] = MFMA_F16(a, wr[nt][kb], aR[nt], 0, 0, 0);
            aZ[nt] = MFMA_F16(a, wz[nt][kb], aZ[nt], 0, 0, 0);
            aN[nt] = MFMA_F16(a, wn[nt][kb], aN[nt], 0, 0, 0);
          }
        }
        const size_t trow = (size_t)(t & 63);
        #pragma unroll
        for (int nt = 0; nt < 2; nt++) {
          _Float16* op = gout + (trow*256 + (2*w + nt)*16 + bb)*768 + l*12;
          half4 vR, vZ, vN;
          #pragma unroll
          for (int i = 0; i < 4; i++) {
            vR[i] = (_Float16)(aR[nt][i] + bR[nt]);
            vZ[i] = (_Float16)(aZ[nt][i] + bZ[nt]);
            vN[i] = (_Float16)(aN[nt][i] + bN[nt]);
          }
          *(half4*)(op)     = vR;
          *(half4*)(op + 4) = vZ;
          *(half4*)(op + 8) = vN;
        }
      }
      __syncthreads();
      if (tid == 0) {
        if (G1) ST_REL(&flag0[bb*2 + par], t0 + 16);
        else    ST_REL(&flag2[bb*2 + par], t0 + 16);
      }
    }
    return;
  }

  // ------------------- GRU roles: 2 bb per block, phase-skewed -------------
  const bool L1 = (role < 8);
  const int pb = L1 ? role*2 : (role - 8)*2;     // bb0; bb1 = pb+1
  const _Float16* gi = L1 ? gi1 : gi2;
  const float* Wf    = L1 ? whh1 : whh2;
  const float* bhh   = L1 ? bhh1 : bhh2;
  float* hcarry      = L1 ? hc1 : hc2;
  const float sc     = __int_as_float(slots[L1 ? 1 : 3]) * (1.0f/127.0f);
  int* fAcq = L1 ? flag0 : flag2;
  int* fPub = L1 ? flag1 : flag3;
  _Float16* hl0 = hl;
  _Float16* hl1 = hl + 4096;

  { // stage initial h for both bb
    int n = tid*8;
    int b = n >> 8, k = n & 255;
    int dst = (k >> 5)*512 + (((k >> 3) & 3)*16 + b)*8;
    #pragma unroll
    for (int bbi = 0; bbi < 2; bbi++) {
      const float4* s4 = (const float4*)&hcarry[(size_t)((pb+bbi)*16 + b)*256 + k];
      float4 v0 = s4[0], v1 = s4[1];
      half8 hv;
      hv[0] = (_Float16)v0.x; hv[1] = (_Float16)v0.y;
      hv[2] = (_Float16)v0.z; hv[3] = (_Float16)v0.w;
      hv[4] = (_Float16)v1.x; hv[5] = (_Float16)v1.y;
      hv[6] = (_Float16)v1.z; hv[7] = (_Float16)v1.w;
      *(half8*)&hl[bbi*4096 + dst] = hv;
    }
  }

  float bN[2];
  float hprev[2][2][4];                          // [bbi][nt][i]
  half8 wr[2][8], wz[2][8], wn[2][8];            // shared by both bb
  int   wr_off[2];
  int   gil[2][2];                               // [bbi][nt]
  #pragma unroll
  for (int nt = 0; nt < 2; nt++) {
    const int j = w*32 + nt*16 + c16;
    bN[nt] = bhh[512 + j];
    #pragma unroll
    for (int bbi = 0; bbi < 2; bbi++) {
      #pragma unroll
      for (int i = 0; i < 4; i++)
        hprev[bbi][nt][i] = hcarry[(size_t)((pb+bbi)*16 + q*4 + i)*256 + j];
      gil[bbi][nt] = ((2*w + nt)*16 + (pb+bbi))*768 + l*12;
    }
    #pragma unroll
    for (int kb = 0; kb < 8; kb++) {
      wr[nt][kb] = qfrag(Wf,      2*w + nt, kb, l, sc);  PIN(wr[nt][kb]);
      wz[nt][kb] = qfrag(Wf, 16 + 2*w + nt, kb, l, sc);  PIN(wz[nt][kb]);
      wn[nt][kb] = qfrag(Wf, 32 + 2*w + nt, kb, l, sc);  PIN(wn[nt][kb]);
    }
    wr_off[nt] = (j >> 5)*512 + ((j >> 3) & 3)*128 + (j & 7);
  }
  _Float16* hq0 = L1 ? (h1seq + (size_t)pb*4096     + tid*8) : (_Float16*)nullptr;
  _Float16* hq1 = L1 ? (h1seq + (size_t)(pb+1)*4096 + tid*8) : (_Float16*)nullptr;

  f32x4 aR0[2], aZ0[2], aN0[2], aR1[2], aZ1[2], aN1[2];
  half4 pR0[2], pZ0[2], pN0[2], pR1[2], pZ1[2], pN1[2];

  auto mfma_ph = [&](const _Float16* hlx, f32x4* aR, f32x4* aZ, f32x4* aN){
    #pragma unroll
    for (int nt = 0; nt < 2; nt++) {
      aR[nt] = (f32x4){0.f,0.f,0.f,0.f};
      aZ[nt] = (f32x4){0.f,0.f,0.f,0.f};
      aN[nt] = (f32x4){0.f,0.f,0.f,0.f};
    }
    #pragma unroll
    for (int kb = 0; kb < 8; kb++) {
      half8 a = *(const half8*)&hlx[kb*512 + l*8];
      #pragma unroll
      for (int nt = 0; nt < 2; nt++) {
        aR[nt] = MFMA_F16(a, wr[nt][kb], aR[nt], 0, 0, 0);
        aZ[nt] = MFMA_F16(a, wz[nt][kb], aZ[nt], 0, 0, 0);
        aN[nt] = MFMA_F16(a, wn[nt][kb], aN[nt], 0, 0, 0);
      }
    }
  };
  auto gate_ph = [&](int bbi, _Float16* hlx, f32x4* aR, f32x4* aZ, f32x4* aN,
                     half4* pR, half4* pZ, half4* pN){
    #pragma unroll
    for (int nt = 0; nt < 2; nt++) {
      #pragma unroll
      for (int i = 0; i < 4; i++) {
        float r  = sigm_f(aR[nt][i] + (float)pR[nt][i]);
        float z  = sigm_f(aZ[nt][i] + (float)pZ[nt][i]);
        float nn = tanh_fast((float)pN[nt][i] + r*(aN[nt][i] + bN[nt]));
        float hp = nn + z*(hprev[bbi][nt][i] - nn);
        hprev[bbi][nt][i] = hp;
        hlx[wr_off[nt] + (q*4 + i)*8] = (_Float16)hp;
      }
    }
  };
  auto pref = [&](int bbi, int t, half4* pR, half4* pZ, half4* pN){
    const _Float16* gbase = gi + (size_t)(t & 63)*196608;
    #pragma unroll
    for (int nt = 0; nt < 2; nt++) {
      const _Float16* gp = gbase + gil[bbi][nt];
      pR[nt] = *(const half4*)(gp);
      pZ[nt] = *(const half4*)(gp + 4);
      pN[nt] = *(const half4*)(gp + 8);
    }
  };

  __syncthreads();                               // staging visible
  if (tid == 0) {                                // acquire group 0, both bb
    while (LD_RLX(&fAcq[pb*2])     < 16) __builtin_amdgcn_s_sleep(10);
    while (LD_RLX(&fAcq[(pb+1)*2]) < 16) __builtin_amdgcn_s_sleep(10);
    (void)LD_ACQ(&fAcq[pb*2]);
  }
  __syncthreads();
  pref(0, 0, pR0, pZ0, pN0);
  mfma_ph(hl0, aR0, aZ0, aN0);                   // MFMA_bb0(0)
  bar_weak();

  for (int t = 0; t < 512; t++) {
    // ======== segA(t): GATE_bb0(t) || MFMA_bb1(t) ========
    if ((t & 15) == 0 && t > 0) {
      if (tid == 0) {
        int par = (t >> 4) & 1;
        while (LD_RLX(&fAcq[pb*2 + par])     < t + 16) __builtin_amdgcn_s_sleep(10);
        while (LD_RLX(&fAcq[(pb+1)*2 + par]) < t + 16) __builtin_amdgcn_s_sleep(10);
        (void)LD_ACQ(&fAcq[pb*2 + par]);
      }
      __syncthreads();
      pref(0, t, pR0, pZ0, pN0);
    }
    if (L1 && t > 0)
      *(half8*)&hq1[(size_t)(t-1)*65536] = *(const half8*)&hl1[tid*8];
    gate_ph(0, hl0, aR0, aZ0, aN0, pR0, pZ0, pN0);
    mfma_ph(hl1, aR1, aZ1, aN1);
    pref(1, t, pR1, pZ1, pN1);
    if ((t & 15) == 0 && t > 0) {
      bar_strong();                              // drains h1seq <= t-1 both bb
      if (tid == 0) { ST_REL(&fPub[pb], t); ST_REL(&fPub[pb+1], t); }
    } else {
      bar_weak();
    }

    // ======== segB(t): MFMA_bb0(t+1) || GATE_bb1(t) ========
    if (L1)
      *(half8*)&hq0[(size_t)t*65536] = *(const half8*)&hl0[tid*8];
    if (t < 511) mfma_ph(hl0, aR0, aZ0, aN0);
    gate_ph(1, hl1, aR1, aZ1, aN1, pR1, pZ1, pN1);
    if (t < 511 && ((t+1) & 15) != 0) pref(0, t+1, pR0, pZ0, pN0);
    bar_weak();
  }
  if (L1)
    *(half8*)&hq1[(size_t)511*65536] = *(const half8*)&hl1[tid*8];
  bar_strong();
  if (tid == 0) { ST_REL(&fPub[pb], 512); ST_REL(&fPub[pb+1], 512); }

  #pragma unroll
  for (int bbi = 0; bbi < 2; bbi++) {
    #pragma unroll
    for (int nt = 0; nt < 2; nt++) {
      const int j = w*32 + nt*16 + c16;
      #pragma unroll
      for (int i = 0; i < 4; i++)
        hcarry[(size_t)((pb+bbi)*16 + q*4 + i)*256 + j] = hprev[bbi][nt][i];
    }
  }
}

// ---------------------------------------------------------------------------
extern "C" void kernel_launch(void* const* d_in, const int* in_sizes, int n_in,
                              void* d_out, int out_size, void* d_ws, size_t ws_size,
                              hipStream_t stream)
{
  const float* x     = (const float*)d_in[0];
  const float* h1_0  = (const float*)d_in[1];
  const float* h2_0  = (const float*)d_in[2];
  const float* w_ih1 = (const float*)d_in[3];
  const float* w_hh1 = (const float*)d_in[4];
  const float* b_ih1 = (const float*)d_in[5];
  const float* b_hh1 = (const float*)d_in[6];
  const float* w_ih2 = (const float*)d_in[7];
  const float* w_hh2 = (const float*)d_in[8];
  const float* b_ih2 = (const float*)d_in[9];
  const float* b_hh2 = (const float*)d_in[10];

  char* ws = (char*)d_ws;
  size_t off = 0;
  auto alloc = [&](size_t bytes) -> void* {
    void* p = ws + off; off += (bytes + 255) & ~(size_t)255; return p;
  };
  int*      slots   = (int*)     alloc(16);
  float*    hc1     = (float*)   alloc(256*256*4);
  float*    hc2     = (float*)   alloc(256*256*4);
  int*      flag0   = (int*)     alloc(32*4);
  int*      flag1   = (int*)     alloc(16*4);
  int*      flag2   = (int*)     alloc(32*4);
  int*      flag3   = (int*)     alloc(16*4);
  _Float16* gi1     = (_Float16*)alloc((size_t)64*393216);    //  25 MB ring
  _Float16* h1seq   = (_Float16*)alloc((size_t)512*131072);   //  67 MB
  _Float16* gi2     = (_Float16*)alloc((size_t)64*393216);    //  25 MB ring
  _Float16* xhbuf   = (_Float16*)alloc((size_t)512*131072);   //  67 MB

  k_maxabs<<<128, 256, 0, stream>>>(w_ih1, w_hh1, w_ih2, w_hh2, 196608, slots);
  k_xcast <<<16384, 256, 0, stream>>>(x, xhbuf);
  (void)hipMemcpyAsync(hc1, h1_0, 256*256*4, hipMemcpyDeviceToDevice, stream);
  (void)hipMemcpyAsync(hc2, h2_0, 256*256*4, hipMemcpyDeviceToDevice, stream);

  k_pipe<<<80, 512, 0, stream>>>(xhbuf, w_ih1, b_ih1, gi1, w_hh1, b_hh1,
                                 hc1, h1seq, w_ih2, b_ih2, b_hh2, w_hh2,
                                 hc2, gi2, slots, flag0, flag1, flag2, flag3);

  (void)hipMemcpyAsync(d_out, hc2, 256*256*4, hipMemcpyDeviceToDevice, stream);
}